// Round 1
// baseline (138.296 us; speedup 1.0000x reference)
//
#include <hip/hip_runtime.h>
#include <math.h>
#include <stdint.h>

typedef __attribute__((ext_vector_type(8))) short short8;
typedef __attribute__((ext_vector_type(4))) float floatx4;

#define LN_EPS 1e-5f
#define ATT_SCALE 0.17677669529663687f  // 32^-0.5

__device__ __constant__ float INVF[8] = {
    1.0f, 0.31622776601683794f, 0.1f, 0.031622776601683794f,
    0.01f, 0.0031622776601683794f, 0.001f, 0.00031622776601683794f};

__device__ inline unsigned short f2bf(float f) {
    unsigned u = __float_as_uint(f);
    u += 0x7fffu + ((u >> 16) & 1u);
    return (unsigned short)(u >> 16);
}

__device__ inline void gl_lds16(const unsigned short* g, unsigned short* l) {
    __builtin_amdgcn_global_load_lds(
        (const __attribute__((address_space(1))) void*)(uintptr_t)g,
        (__attribute__((address_space(3))) void*)(uintptr_t)l, 16, 0, 0);
}

// stage one 64x256 bf16 weight tile (rows of W) into a 32KB LDS buffer.
// LDS dest is wave-uniform base + lane*16 (global src pre-swizzled to match
// the swizzled ds_read pattern used by the MFMA loops).
__device__ inline void stage_tile(const unsigned short* __restrict__ Wsrc,
                                  unsigned short* dst, int w, int lane) {
    #pragma unroll
    for (int i = 0; i < 4; ++i) {
        int rbase = i * 16 + w * 2;
        int row = rbase + (lane >> 5);
        int sl = lane & 31;
        int c = (sl & ~7) | ((sl & 7) ^ (row & 7));
        gl_lds16(Wsrc + (size_t)row * 256 + c * 8, dst + rbase * 256);
    }
}

// raw-barrier pipeline primitives: NEVER use __syncthreads() in the pipelined
// loops (it drains vmcnt(0) and kills the prefetch).
#define VM0() asm volatile("s_waitcnt vmcnt(0)" ::: "memory")
#define LG0() asm volatile("s_waitcnt lgkmcnt(0)" ::: "memory")
#define SBAR()                                 \
    do {                                       \
        __builtin_amdgcn_s_barrier();          \
        __builtin_amdgcn_sched_barrier(0);     \
    } while (0)

// ---------------- prep: weights fp32 -> bf16 (packed stores) --------------
__global__ __launch_bounds__(256)
void prep_w(const float* __restrict__ wq, const float* __restrict__ wo,
            unsigned short* __restrict__ bq, unsigned short* __restrict__ bo) {
    int g = blockIdx.x * 256 + threadIdx.x;  // 65536 groups of 4
    const float* src;
    unsigned short* dst;
    if (g < 49152) { src = wq + (size_t)g * 4; dst = bq + (size_t)g * 4; }
    else { int h = g - 49152; src = wo + (size_t)h * 4; dst = bo + (size_t)h * 4; }
    float4 v = *(const float4*)src;
    uint2 o;
    o.x = (unsigned)f2bf(v.x) | ((unsigned)f2bf(v.y) << 16);
    o.y = (unsigned)f2bf(v.z) | ((unsigned)f2bf(v.w) << 16);
    *(uint2*)dst = o;
}

// ---------------- fused kernel: one block per (b,x), 512 thr = 8 waves ----
__global__ __launch_bounds__(512, 2)
void fused_kernel(const float* __restrict__ pair_act, const int* __restrict__ mask,
                  const float* __restrict__ gamma, const float* __restrict__ beta,
                  const unsigned short* __restrict__ Wqkv,
                  const unsigned short* __restrict__ Wout,
                  float* __restrict__ out) {
    // Weight-tile double buffer (tile t lives in S16[(t+1)&1]); S16[0] doubles
    // as the LN exchange buffer before the GEMM loop starts.
    __shared__ __align__(16) unsigned short S16[2][16384];  // 64 KB
    __shared__ __align__(16) unsigned short Ks[2][128 * 40]; // 20 KB
    __shared__ __align__(16) unsigned short Vt[2][32 * 136]; // 17 KB
    __shared__ __align__(16) unsigned short Qall[8 * 640];   // 10 KB

    int bx = blockIdx.x;
    int tid = threadIdx.x;
    int w = tid >> 6, lane = tid & 63, qd = lane >> 4, lo = lane & 15;
    unsigned short* Qscr = Qall + w * 640;

    float tX = -1.0f + (2.0f / 127.0f) * (float)(bx & 127);

    // Prefetch QKV weight tile 0 into S16[1]; lands under the LN phase.
    stage_tile(Wqkv, &S16[1][0], w, lane);

    float msel[8];
    #pragma unroll
    for (int nt = 0; nt < 8; ++nt)
        msel[nt] = mask[bx * 128 + nt * 16 + lo] ? 0.0f : 1.0f;

    // ---------- Phase 0: LayerNorm, all 512 threads; 2 column-half passes --
    short8 a_frag[8];
    {
        int rl = tid >> 2, q0 = tid & 3;  // row 0..127, quarter 0..3
        const float* src = pair_act + ((size_t)(bx * 128 + rl)) * 256 + q0 * 4;
        float4 v[16];
        float s = 0.f;
        #pragma unroll
        for (int u = 0; u < 16; ++u) {
            v[u] = *(const float4*)(src + u * 16);
            s += v[u].x + v[u].y + v[u].z + v[u].w;
        }
        s += __shfl_xor(s, 1);
        s += __shfl_xor(s, 2);
        float mean = s * (1.0f / 256.0f);
        float sq = 0.f;
        #pragma unroll
        for (int u = 0; u < 16; ++u) {
            float d0 = v[u].x - mean, d1 = v[u].y - mean;
            float d2 = v[u].z - mean, d3 = v[u].w - mean;
            sq += d0 * d0 + d1 * d1 + d2 * d2 + d3 * d3;
        }
        sq += __shfl_xor(sq, 1);
        sq += __shfl_xor(sq, 2);
        float rs = rsqrtf(sq * (1.0f / 256.0f) + LN_EPS);

        int rw = 16 * w + lo;
        #pragma unroll
        for (int p = 0; p < 2; ++p) {
            #pragma unroll
            for (int ul = 0; ul < 8; ++ul) {
                int u = p * 8 + ul;
                float4 g4 = *(const float4*)(gamma + q0 * 4 + u * 16);
                float4 b4 = *(const float4*)(beta + q0 * 4 + u * 16);
                unsigned e0 = f2bf((v[u].x - mean) * rs * g4.x + b4.x);
                unsigned e1 = f2bf((v[u].y - mean) * rs * g4.y + b4.y);
                unsigned e2 = f2bf((v[u].z - mean) * rs * g4.z + b4.z);
                unsigned e3 = f2bf((v[u].w - mean) * rs * g4.w + b4.w);
                int cw = 2 * ul + (q0 >> 1);
                int ss = (cw & ~7) | ((cw & 7) ^ (rl & 7));
                uint2 pk;
                pk.x = e0 | (e1 << 16);
                pk.y = e2 | (e3 << 16);
                *(uint2*)&S16[0][rl * 128 + ss * 8 + (q0 & 1) * 4] = pk;
            }
            __syncthreads();
            #pragma unroll
            for (int cp = 0; cp < 4; ++cp) {
                int ci = cp * 4 + qd;
                int ss = (ci & ~7) | ((ci & 7) ^ (rw & 7));
                a_frag[p * 4 + cp] = *(const short8*)&S16[0][rw * 128 + ss * 8];
            }
            __syncthreads();
        }
    }

    // ---------- Phase 1: QKV GEMM, 12 tiles, depth-1 prefetch pipeline -----
    // tile t = part*4 + hc covers W rows [t*64, t*64+64): q tiles 0-3,
    // k tiles 4-7, v tiles 8-11.  All results held in registers.
    unsigned q_pk[4][4][2], k_pk[4][4][2], v_pk[4][4][2];
    #pragma unroll
    for (int t = 0; t < 12; ++t) {
        VM0();   // my tile-t loads landed (issued one full phase ago)
        SBAR();  // all waves: tile t resident; compute(t-1) reads done
        // stage tile t+1 (or Wout tile 0 on the last iter) into the buffer
        // that compute(t-1) just freed.
        const unsigned short* nsrc =
            (t < 11) ? (Wqkv + (size_t)(t + 1) * 64 * 256) : Wout;
        stage_tile(nsrc, &S16[t & 1][0], w, lane);

        const unsigned short* Sb = &S16[(t + 1) & 1][0];
        floatx4 acc[4];
        #pragma unroll
        for (int tq = 0; tq < 4; ++tq) acc[tq] = (floatx4){0.f, 0.f, 0.f, 0.f};
        #pragma unroll
        for (int cc = 0; cc < 8; ++cc) {
            #pragma unroll
            for (int tq = 0; tq < 4; ++tq) {
                int rw2 = tq * 16 + lo;
                int ci = cc * 4 + qd;
                int ss = (ci & ~7) | ((ci & 7) ^ (rw2 & 7));
                short8 bf = *(const short8*)&Sb[rw2 * 256 + ss * 8];
                acc[tq] = __builtin_amdgcn_mfma_f32_16x16x32_bf16(
                    a_frag[cc], bf, acc[tq], 0, 0, 0);
            }
        }
        // rotary on cols 0..31 of q (tile 0) and k (tile 4)
        if (t == 0 || t == 4) {
            #pragma unroll
            for (int tc = 0; tc < 2; ++tc) {
                int pi = (tc * 16 + lo) >> 1;
                float invf = INVF[pi & 7];
                float sgn = (lo & 1) ? 1.0f : -1.0f;
                #pragma unroll
                for (int r = 0; r < 4; ++r) {
                    int y = 16 * w + qd * 4 + r;
                    float tp = (pi < 8) ? tX
                                        : (-1.0f + (2.0f / 127.0f) * (float)y);
                    float sn, cs;
                    __sincosf(tp * invf, &sn, &cs);
                    float vv = acc[tc][r];
                    float pv = __shfl_xor(vv, 1);
                    acc[tc][r] = vv * cs + sgn * pv * sn;
                }
            }
        }
        int part = t >> 2, hc = t & 3;
        #pragma unroll
        for (int tq = 0; tq < 4; ++tq) {
            unsigned p0 = (unsigned)f2bf(acc[tq][0]) |
                          ((unsigned)f2bf(acc[tq][1]) << 16);
            unsigned p1 = (unsigned)f2bf(acc[tq][2]) |
                          ((unsigned)f2bf(acc[tq][3]) << 16);
            if (part == 0) { q_pk[hc][tq][0] = p0; q_pk[hc][tq][1] = p1; }
            else if (part == 1) { k_pk[hc][tq][0] = p0; k_pk[hc][tq][1] = p1; }
            else { v_pk[hc][tq][0] = p0; v_pk[hc][tq][1] = p1; }
        }
    }

    // ---------- Phase 2: attention, K/V double-buffered, 1 barrier/head ----
    // pre-loop: head 0's K/V into buffer 0
    {
        #pragma unroll
        for (int tt = 0; tt < 2; ++tt) {
            int tC = tt;  // head 0: hc=0, tt0=0
            int d = tt * 16 + lo;
            #pragma unroll
            for (int r = 0; r < 4; ++r) {
                unsigned kv = (k_pk[0][tC][r >> 1] >> ((r & 1) * 16)) & 0xffffu;
                Ks[0][(16 * w + qd * 4 + r) * 40 + d] = (unsigned short)kv;
            }
            uint2 pv;
            pv.x = v_pk[0][tC][0];
            pv.y = v_pk[0][tC][1];
            *(uint2*)&Vt[0][d * 136 + 16 * w + qd * 4] = pv;
        }
    }
    LG0();   // flush K/V writes
    SBAR();  // also: compute(11) reads of S16[0] done -> safe to stage there
    // Wout tile 1 -> S16[0]; tile 0 is already in flight to S16[1].
    stage_tile(Wout + (size_t)64 * 256, &S16[0][0], w, lane);

    short8 of[8];  // out-GEMM A-fragments, one per head
    #pragma unroll
    for (int h = 0; h < 8; ++h) {
        // stage next head's K/V into the alternate buffer (overlaps compute)
        if (h < 7) {
            int g = h + 1, hcg = g >> 1, tg0 = (g & 1) * 2, kb = g & 1;
            #pragma unroll
            for (int tt = 0; tt < 2; ++tt) {
                int tC = tg0 + tt;
                int d = tt * 16 + lo;
                #pragma unroll
                for (int r = 0; r < 4; ++r) {
                    unsigned kv =
                        (k_pk[hcg][tC][r >> 1] >> ((r & 1) * 16)) & 0xffffu;
                    Ks[kb][(16 * w + qd * 4 + r) * 40 + d] = (unsigned short)kv;
                }
                uint2 pv;
                pv.x = v_pk[hcg][tC][0];
                pv.y = v_pk[hcg][tC][1];
                *(uint2*)&Vt[kb][d * 136 + 16 * w + qd * 4] = pv;
            }
        }
        // compute head h from buffer h&1
        {
            int hch = h >> 1, cb = h & 1;
            #pragma unroll
            for (int tt = 0; tt < 2; ++tt) {
                int tC = (h & 1) * 2 + tt;
                #pragma unroll
                for (int r = 0; r < 4; ++r) {
                    unsigned qv =
                        (q_pk[hch][tC][r >> 1] >> ((r & 1) * 16)) & 0xffffu;
                    Qscr[(qd * 4 + r) * 40 + tt * 16 + lo] = (unsigned short)qv;
                }
            }
            short8 aq = *(const short8*)&Qscr[lo * 40 + qd * 8];
            float ef[8][4];
            float sums[4] = {0.f, 0.f, 0.f, 0.f};
            #pragma unroll
            for (int nt = 0; nt < 8; ++nt) {
                short8 bk = *(const short8*)&Ks[cb][(nt * 16 + lo) * 40 + qd * 8];
                floatx4 c = (floatx4){0.f, 0.f, 0.f, 0.f};
                c = __builtin_amdgcn_mfma_f32_16x16x32_bf16(aq, bk, c, 0, 0, 0);
                #pragma unroll
                for (int r = 0; r < 4; ++r) {
                    float e = __expf(c[r] * ATT_SCALE) * msel[nt];
                    ef[nt][r] = e;
                    sums[r] += e;
                }
            }
            float inv[4];
            #pragma unroll
            for (int r = 0; r < 4; ++r) {
                float vv = sums[r];
                vv += __shfl_xor(vv, 1);
                vv += __shfl_xor(vv, 2);
                vv += __shfl_xor(vv, 4);
                vv += __shfl_xor(vv, 8);
                inv[r] = 1.0f / vv;
            }
            floatx4 o2[2];
            o2[0] = (floatx4){0.f, 0.f, 0.f, 0.f};
            o2[1] = (floatx4){0.f, 0.f, 0.f, 0.f};
            #pragma unroll
            for (int c2 = 0; c2 < 4; ++c2) {
                #pragma unroll
                for (int half = 0; half < 2; ++half) {
                    int nt = c2 * 2 + half;
                    #pragma unroll
                    for (int r = 0; r < 4; ++r)
                        Qscr[(qd * 4 + r) * 40 + half * 16 + lo] =
                            f2bf(ef[nt][r]);
                }
                short8 pa = *(const short8*)&Qscr[lo * 40 + qd * 8];
                #pragma unroll
                for (int n = 0; n < 2; ++n) {
                    short8 vb = *(const short8*)&Vt[cb][(n * 16 + lo) * 136 +
                                                       c2 * 32 + qd * 8];
                    o2[n] = __builtin_amdgcn_mfma_f32_16x16x32_bf16(pa, vb,
                                                                    o2[n], 0, 0, 0);
                }
            }
            #pragma unroll
            for (int n = 0; n < 2; ++n)
                #pragma unroll
                for (int r = 0; r < 4; ++r)
                    Qscr[(qd * 4 + r) * 40 + n * 16 + lo] =
                        f2bf(o2[n][r] * inv[r]);
            of[h] = *(const short8*)&Qscr[lo * 40 + qd * 8];
        }
        LG0();               // K/V writes for head h+1 visible
        if (h == 7) VM0();   // Wout tiles 0,1 resident (issued long ago: free)
        SBAR();
    }

    // ---------- Phase 3: out GEMM, 4 tiles, pipelined ---------------------
    #pragma unroll
    for (int nc = 0; nc < 4; ++nc) {
        if (nc) {
            VM0();   // tile nc resident (nc<2: pre-staged; nc>=2: one phase old)
            SBAR();  // compute(nc-1) reads done -> its buffer is free
            if (nc < 3)
                stage_tile(Wout + (size_t)(nc + 1) * 64 * 256,
                           &S16[nc & 1][0], w, lane);
        }
        const unsigned short* Sb = &S16[(nc + 1) & 1][0];
        floatx4 acc[4];
        #pragma unroll
        for (int tq = 0; tq < 4; ++tq) acc[tq] = (floatx4){0.f, 0.f, 0.f, 0.f};
        #pragma unroll
        for (int cc = 0; cc < 8; ++cc) {
            #pragma unroll
            for (int tq = 0; tq < 4; ++tq) {
                int rw2 = tq * 16 + lo;
                int ci = cc * 4 + qd;
                int ss = (ci & ~7) | ((ci & 7) ^ (rw2 & 7));
                short8 bf = *(const short8*)&Sb[rw2 * 256 + ss * 8];
                acc[tq] = __builtin_amdgcn_mfma_f32_16x16x32_bf16(
                    of[cc], bf, acc[tq], 0, 0, 0);
            }
        }
        #pragma unroll
        for (int tq = 0; tq < 4; ++tq)
            #pragma unroll
            for (int r = 0; r < 4; ++r)
                out[(size_t)(bx * 128 + 16 * w + qd * 4 + r) * 256 + nc * 64 +
                    tq * 16 + lo] = acc[tq][r];
    }
}

extern "C" void kernel_launch(void* const* d_in, const int* in_sizes, int n_in,
                              void* d_out, int out_size, void* d_ws, size_t ws_size,
                              hipStream_t stream) {
    const float* pair_act = (const float*)d_in[0];
    const int* pair_mask = (const int*)d_in[1];
    const float* ln_gamma = (const float*)d_in[2];
    const float* ln_beta = (const float*)d_in[3];
    const float* Wqkv = (const float*)d_in[4];
    const float* Wout = (const float*)d_in[5];
    float* out = (float*)d_out;

    char* ws = (char*)d_ws;
    unsigned short* wqkv_bf = (unsigned short*)ws;            // 393,216 B
    unsigned short* wout_bf = (unsigned short*)(ws + 393216); // 131,072 B

    prep_w<<<256, 256, 0, stream>>>(Wqkv, Wout, wqkv_bf, wout_bf);
    fused_kernel<<<256, 512, 0, stream>>>(pair_act, pair_mask, ln_gamma, ln_beta,
                                          wqkv_bf, wout_bf, out);
}